// Round 10
// baseline (510.248 us; speedup 1.0000x reference)
//
#include <hip/hip_runtime.h>

// ---------------- problem constants ----------------
#define N_WORDS 16384
#define MAXL    16
#define VOCABSZ 128
#define EMBD    64
#define HID     256
#define GATES   1024        // 4*HID
#define AROW    264         // A row stride in shorts (h only: 256 + 8 pad)
#define M_TILE  32          // words per workgroup
#define NT      512         // word tiles (N_WORDS / M_TILE)

typedef __attribute__((ext_vector_type(8))) short bf16x8;  // 8 bf16 = 4 VGPRs
typedef __attribute__((ext_vector_type(4))) float f32x4;
typedef __attribute__((ext_vector_type(2))) float f32x2;
typedef __attribute__((ext_vector_type(4))) int   i32x4;

// ---------------- workspace layout (bytes) ----------------
// wsw : swizzled Whh weights, A-fragment order: [dir][R 0..63][kk 0..7][lane][8 bf16]
// xg  : per-char gate table: [dir][char][4*unit+type] = b_ih+b_hh + emb[c]@Wih^T (fp32)
#define OFF_WSW   0ul          // 2*64*8*64*16 = 1048576
#define OFF_XG    1048576ul    // 2*128*1024*4 = 1048576
#define OFF_SORT  2097152ul    // 16384 ints = 65536
// cell state lives in LDS -- no global c buffer

__device__ inline short tobf(float f) {           // fp32 -> bf16 RNE
  unsigned u = __float_as_uint(f);
  unsigned r = (u + 0x7fffu + ((u >> 16) & 1u)) >> 16;
  return (short)r;
}
// raw transcendental units via inline asm
__device__ inline float aexp2(float x) { float r; asm("v_exp_f32 %0, %1" : "=v"(r) : "v"(x)); return r; }
__device__ inline float arcp(float x)  { float r; asm("v_rcp_f32 %0, %1" : "=v"(r) : "v"(x)); return r; }
__device__ inline float fsig(float x)   { return arcp(1.0f + aexp2(x * -1.4426950408889634f)); }
__device__ inline float ftanhf(float x) { return 1.0f - 2.0f * arcp(1.0f + aexp2(x * 2.8853900817779268f)); }

// ---------------- fused prep (1 launch) -------------------------------------
// blocks 0..255    : Whh swizzle into MFMA A-fragment layout (kk 0..7 only)
// blocks 256..1279 : xg char-gate table (fp32-exact x contribution + bias)
// block  1280      : single-block length-bucket sort (bin order arbitrary)
__global__ void prep_all(const float* __restrict__ Wihf, const float* __restrict__ Whhf,
                         const float* __restrict__ Wihb, const float* __restrict__ Whhb,
                         const float* __restrict__ emb,
                         const float* __restrict__ bihf, const float* __restrict__ bhhf,
                         const float* __restrict__ bihb, const float* __restrict__ bhhb,
                         const int* __restrict__ lengths,
                         short* __restrict__ wsw, float* __restrict__ xg,
                         int* __restrict__ sorted) {
  __shared__ int hist[16], base[16], cnt[16];
  int blk = blockIdx.x;
  if (blk < 256) {            // Whh swizzle: 2*64*8*64 = 65536 fragments
    int id = blk * 256 + threadIdx.x;
    int d    = id >> 15;
    int r    = id & 32767;
    int R    = r >> 9;
    int r2   = r & 511;
    int kk   = r2 >> 6;
    int lane = r2 & 63;
    int m    = lane & 15;
    int unit = R * 4 + (m >> 2);
    int ty   = m & 3;
    int g    = ty * 256 + unit;
    int kb   = kk * 32 + (lane >> 4) * 8;
    const float* Whh = d ? Whhb : Whhf;
    bf16x8 v;
#pragma unroll
    for (int j = 0; j < 8; ++j) v[j] = tobf(Whh[g * HID + kb + j]);
    ((bf16x8*)wsw)[id] = v;
  } else if (blk < 1280) {    // xg table: 2*128*1024 entries, fp32-exact
    int id = (blk - 256) * 256 + threadIdx.x;   // 0..262143
    int d  = id >> 17;
    int r  = id & 131071;
    int c  = r >> 10;
    int n  = r & 1023;                          // interleaved 4*unit+type
    int u  = n >> 2, ty = n & 3;
    int g  = ty * 256 + u;
    const float* Wih = d ? Wihb : Wihf;
    const float* bi  = d ? bihb : bihf;
    const float* bh  = d ? bhhb : bhhf;
    const f32x4* e4 = (const f32x4*)(emb + c * EMBD);
    const f32x4* w4 = (const f32x4*)(Wih + g * EMBD);
    f32x4 a = {0.f, 0.f, 0.f, 0.f};
#pragma unroll
    for (int i = 0; i < 16; ++i) a += e4[i] * w4[i];
    xg[id] = bi[g] + bh[g] + a[0] + a[1] + a[2] + a[3];
  } else {                    // length-bucket sort, 256 threads
    int tid = threadIdx.x;
    if (tid < 16) { hist[tid] = 0; cnt[tid] = 0; }
    __syncthreads();
    for (int i = tid; i < N_WORDS; i += 256)
      atomicAdd(&hist[lengths[i] - 1], 1);
    __syncthreads();
    if (tid == 0) {
      int s = 0;
      for (int b = 0; b < 16; ++b) { base[b] = s; s += hist[b]; }
    }
    __syncthreads();
    for (int i = tid; i < N_WORDS; i += 256) {
      int b = lengths[i] - 1;
      int p = base[b] + atomicAdd(&cnt[b], 1);
      sorted[p] = i;
    }
  }
}

// ---------------- main fused BiLSTM kernel ----------------
// R10 vs R8: x-matmul ELIMINATED -- gates' x-part + bias comes from the xg
// char-table (fp32-exact, L2-hot). K 320 -> 256: MFMA -20%, hx 80 -> 64 regs,
// no embw gather / x staging / bias staging; A holds h only (52 KB LDS total).
// Both barriers are lgkm-only (no global data crosses waves) so weight/xg
// prefetch stays in flight across steps. Epilogue adds xg before activations.
// Layout (R8-proven): lane owns unit 64wv+4rt+quad, word ct*16+colc;
// acc regs = i,f,g,o. Cell state: LDS f32x2 per (wv,rt,lane).
__global__ __launch_bounds__(256, 2) void lstm_main(
    const int* __restrict__ char_ids, const int* __restrict__ lengths,
    const short* __restrict__ wsw, const float* __restrict__ xg,
    const int* __restrict__ sorted, float* __restrict__ out) {
  __shared__ __align__(16) short A[M_TILE * AROW];   // [word][h(256)+pad] 16.9 KB
  __shared__ __align__(16) int   charl[M_TILE * 16]; // 2 KB
  __shared__ __align__(8)  f32x2 c4[4 * 16 * 64];    // [wv][rt][lane] cell, 32 KB
  __shared__ int lenl[M_TILE];
  __shared__ int swl[M_TILE];

  const int tid  = threadIdx.x;
  const int lane = tid & 63;
  const int wv   = tid >> 6;            // 0..3
  const int quad = lane >> 4;
  const int colc = lane & 15;
  const int pb   = blockIdx.x;
  const int dir  = pb & 1;
  const int qb   = pb >> 1;
  const int tile = (qb & 1) ? (511 - (qb >> 1)) : (qb >> 1);

  if (tid < M_TILE) {
    int sw = sorted[tile * M_TILE + tid];
    swl[tid]  = sw;
    lenl[tid] = lengths[sw];
  }
  for (int i = tid; i < M_TILE * AROW / 2; i += 256) ((int*)A)[i] = 0;     // h=0
  for (int i = tid; i < 4 * 16 * 64; i += 256) c4[i] = (f32x2){0.f, 0.f};  // c=0
  __syncthreads();

  if (tid < 128) { // char ids for the tile (via sorted ids): 32 words x 16
    int w = tid >> 2, ch = tid & 3;
    ((i32x4*)charl)[tid] = ((const i32x4*)(char_ids + swl[w] * 16))[ch];
  }
  int Lmax = lenl[lane & 31];
  for (int o = 32; o; o >>= 1) { int v = __shfl_xor(Lmax, o, 64); Lmax = Lmax > v ? Lmax : v; }
  __syncthreads();  // charl ready

  // step-invariant lane constants (word dimension, per col-tile ct)
  int lenw[2], hadrb[2], oadr[2];
#pragma unroll
  for (int ct = 0; ct < 2; ++ct) {
    int wl = ct * 16 + colc;
    lenw[ct]  = lenl[wl];
    hadrb[ct] = wl * AROW + 64 * wv + quad;                  // + 4*rt : bf16 h slot
    oadr[ct]  = swl[wl] * 512 + dir * 256 + 64 * wv + quad;  // + 4*rt : fp32 out
  }
  const short* wp  = wsw + ((size_t)(dir * 64 + wv * 16)) * 4096 + lane * 8;
  const float* xga = xg + dir * (VOCABSZ * GATES);
  f32x2* cptr = c4 + wv * (16 * 64) + lane;   // + rt*64

  // per-step xg row bases (char-dependent); clamped pos for dead steps is
  // harmless: always-write epilogue, out captured only at t==len-1.
  auto calc_cc = [&](int tt, int (&c2a)[2]) {
#pragma unroll
    for (int ct = 0; ct < 2; ++ct) {
      int len = lenw[ct];
      int pos = (dir == 0) ? tt : (len - 1 - tt);
      pos = pos < 0 ? 0 : (pos > 15 ? 15 : pos);
      c2a[ct] = charl[(ct * 16 + colc) * 16 + pos] * GATES + 256 * wv + 4 * quad;
    }
  };
  int cc[2];
  calc_cc(0, cc);

  __syncthreads();  // zeros visible

  // preload rt=0 weight fragments once; ping-pong keeps them hot across steps
  bf16x8 wA[8], wB[8];
#pragma unroll
  for (int kk = 0; kk < 8; ++kk) wA[kk] = *(const bf16x8*)(wp + kk * 512);

#pragma unroll 1
  for (int t = 0; t < Lmax; ++t) {
    bf16x8 hx[2][8];  // B fragments: lane = B[k = kk*32 + quad*8 + j][n = ct*16+colc]
#pragma unroll
    for (int ct = 0; ct < 2; ++ct)
#pragma unroll
      for (int kk = 0; kk < 8; ++kk)
        hx[ct][kk] = *(const bf16x8*)(A + (ct * 16 + colc) * AROW + kk * 32 + quad * 8);

    // lgkm-only barrier: all waves snapshotted h; vmem prefetch stays in flight
    asm volatile("s_waitcnt lgkmcnt(0)\n\ts_barrier" ::: "memory");

    auto wtile = [&](int rt, bf16x8(&wc)[8], bf16x8(&wn)[8], int pre) {
      // prefetch next tile's weights (pre=0 at rt=15 warms next step's rt0)
#pragma unroll
      for (int kk = 0; kk < 8; ++kk) wn[kk] = *(const bf16x8*)(wp + (pre * 8 + kk) * 512);
      // this tile's xg (x-part + bias): issued now, consumed in epilogue (~8 MFMA later)
      f32x4 xgv0 = *(const f32x4*)(xga + cc[0] + 16 * rt);
      f32x4 xgv1 = *(const f32x4*)(xga + cc[1] + 16 * rt);
      f32x2 co2 = cptr[rt * 64];                 // LDS c, covered by the MFMA block
      f32x4 acc[2];
#pragma unroll
      for (int ct = 0; ct < 2; ++ct) acc[ct] = (f32x4){0.f, 0.f, 0.f, 0.f};
#pragma unroll
      for (int kk = 0; kk < 8; ++kk)
#pragma unroll
        for (int ct = 0; ct < 2; ++ct)  // 2 independent acc chains
          acc[ct] = __builtin_amdgcn_mfma_f32_16x16x32_bf16(wc[kk], hx[ct][kk], acc[ct], 0, 0, 0);

      f32x2 cnew;
#pragma unroll
      for (int ct = 0; ct < 2; ++ct) {
        f32x4 g4 = acc[ct] + (ct ? xgv1 : xgv0);
        // lane-private epilogue: g4 = i,f,g,o of (unit 64wv+4rt+quad, word ct*16+colc)
        // always-write: masked words' h/c are don't-care (bounded, never output)
        float ig = fsig(g4[0]);
        float fg = fsig(g4[1]);
        float gg = ftanhf(g4[2]);
        float og = fsig(g4[3]);
        float c2 = fg * co2[ct] + ig * gg;
        float h2 = og * ftanhf(c2);
        cnew[ct] = c2;
        A[hadrb[ct] + 4 * rt] = tobf(h2);
        if (t == lenw[ct] - 1) out[oadr[ct] + 4 * rt] = h2;  // final h in fp32
      }
      cptr[rt * 64] = cnew;   // one ds_write_b64 (own slice, no hazard)
    };

#pragma unroll 1
    for (int rt2 = 0; rt2 < 16; rt2 += 2) {  // ping-pong weight buffers, static idx
      wtile(rt2,     wA, wB, rt2 + 1);
      wtile(rt2 + 1, wB, wA, (rt2 + 2) & 15);
    }

    calc_cc(t + 1, cc);   // next step's xg row bases (charl is read-only)
    // lgkm-only barrier: h/c LDS writes visible; weight prefetch uninterrupted
    asm volatile("s_waitcnt lgkmcnt(0)\n\ts_barrier" ::: "memory");
  }
}

// ---------------- launch ----------------
extern "C" void kernel_launch(void* const* d_in, const int* in_sizes, int n_in,
                              void* d_out, int out_size, void* d_ws, size_t ws_size,
                              hipStream_t stream) {
  const int*   char_ids = (const int*)d_in[0];
  const int*   lengths  = (const int*)d_in[1];
  const float* emb      = (const float*)d_in[2];
  const float* Wihf     = (const float*)d_in[3];
  const float* Whhf     = (const float*)d_in[4];
  const float* bihf     = (const float*)d_in[5];
  const float* bhhf     = (const float*)d_in[6];
  const float* Wihb     = (const float*)d_in[7];
  const float* Whhb     = (const float*)d_in[8];
  const float* bihb     = (const float*)d_in[9];
  const float* bhhb     = (const float*)d_in[10];

  char* ws = (char*)d_ws;
  short* wsw   = (short*)(ws + OFF_WSW);
  float* xg    = (float*)(ws + OFF_XG);
  int*   sortd = (int*)(ws + OFF_SORT);

  prep_all<<<1281, 256, 0, stream>>>(Wihf, Whhf, Wihb, Whhb, emb,
                                     bihf, bhhf, bihb, bhhb, lengths,
                                     wsw, xg, sortd);
  lstm_main<<<1024, 256, 0, stream>>>(char_ids, lengths, wsw, xg, sortd,
                                      (float*)d_out);
}